// Round 10
// baseline (83.208 us; speedup 1.0000x reference)
//
#include <hip/hip_runtime.h>

typedef __attribute__((ext_vector_type(8))) short bf16x8;
typedef __attribute__((ext_vector_type(4))) float f32x4;

static constexpr int N_NODES = 8192;   // B*L
static constexpr int FEAT    = 128;
static constexpr int NB      = 16;     // nodes per gather block
static constexpr int NBLK    = N_NODES / NB;   // 512 blocks
static constexpr int FEAT_BLOCKS = 6250;  // 100000*128/8 floats / 256 threads

__device__ __forceinline__ unsigned short f2bf(float f) {
    unsigned u = __builtin_bit_cast(unsigned, f);
    u += 0x7FFFu + ((u >> 16) & 1u);   // round-to-nearest-even
    return (unsigned short)(u >> 16);
}
__device__ __forceinline__ float bf2f(unsigned short h) {
    return __builtin_bit_cast(float, ((unsigned)h) << 16);
}
__device__ __forceinline__ void acc8(float* a, const uint4 v) {
    a[0] += bf2f((unsigned short)(v.x & 0xffffu));
    a[1] += bf2f((unsigned short)(v.x >> 16));
    a[2] += bf2f((unsigned short)(v.y & 0xffffu));
    a[3] += bf2f((unsigned short)(v.y >> 16));
    a[4] += bf2f((unsigned short)(v.z & 0xffffu));
    a[5] += bf2f((unsigned short)(v.z >> 16));
    a[6] += bf2f((unsigned short)(v.w & 0xffffu));
    a[7] += bf2f((unsigned short)(v.w >> 16));
}
__device__ __forceinline__ uint4 pack8(const float* a, float sc) {
    uint4 o;
    o.x = (unsigned)f2bf(a[0] * sc) | ((unsigned)f2bf(a[1] * sc) << 16);
    o.y = (unsigned)f2bf(a[2] * sc) | ((unsigned)f2bf(a[3] * sc) << 16);
    o.z = (unsigned)f2bf(a[4] * sc) | ((unsigned)f2bf(a[5] * sc) << 16);
    o.w = (unsigned)f2bf(a[6] * sc) | ((unsigned)f2bf(a[7] * sc) << 16);
    return o;
}

// ---------------- Kernel 0: pack features + W fp32 -> bf16 ----------------
__global__ void __launch_bounds__(256) pack_all(
    const float* __restrict__ feat, const float* __restrict__ lw,
    unsigned short* __restrict__ T, unsigned short* __restrict__ Wp)
{
    const int b = blockIdx.x;
    if (b < FEAT_BLOCKS) {
        const size_t i = (size_t)b * 256 + threadIdx.x;
        const f32x4* src = (const f32x4*)feat;
        const f32x4 v0 = __builtin_nontemporal_load(src + i * 2);
        const f32x4 v1 = __builtin_nontemporal_load(src + i * 2 + 1);
        ushort4 o0, o1;
        o0.x = f2bf(v0[0]); o0.y = f2bf(v0[1]); o0.z = f2bf(v0[2]); o0.w = f2bf(v0[3]);
        o1.x = f2bf(v1[0]); o1.y = f2bf(v1[1]); o1.z = f2bf(v1[2]); o1.w = f2bf(v1[3]);
        ((ushort4*)T)[i * 2]     = o0;
        ((ushort4*)T)[i * 2 + 1] = o1;
    } else {
        const int i = (b - FEAT_BLOCKS) * 256 + threadIdx.x;
        const float4 v = ((const float4*)lw)[i];
        ushort4 o;
        o.x = f2bf(v.x); o.y = f2bf(v.y); o.z = f2bf(v.z); o.w = f2bf(v.w);
        ((ushort4*)Wp)[i] = o;
    }
}

// ---------------- Kernel 1: 16-node gather (round-9 phases 1-2, global F out) ----
// Block: 16 nodes, 256 threads. Group g (16 lanes) = one node; lane covers 8 dims.
// F layout (round-8): three j-major [8192][128] bf16 matrices F0/F1/F2.
__global__ void __launch_bounds__(256) gather16(
    const unsigned short* __restrict__ T,
    const int*   __restrict__ nodes,
    const int*   __restrict__ n1,
    const int*   __restrict__ n2,
    unsigned short* __restrict__ F0,
    unsigned short* __restrict__ F1,
    unsigned short* __restrict__ F2)
{
    __shared__ int nfs[NB];
    __shared__ int sm_m[NB][10];
    __shared__ int idx[NB][112];   // [0..9]=1hop, [10..109]=2hop, [110]=self

    const int blk = blockIdx.x;
    const int tid = threadIdx.x;

    // ---- phase 1: indices (identical to round-9) ----
    if (tid < NB) nfs[tid] = nodes[blk * NB + tid];
    __syncthreads();
    if (tid < NB * 10) {                       // 160 threads: 1-hop
        const int i = tid / 10, s = tid - (tid / 10) * 10;
        idx[i][s] = n1[nfs[i] * 10 + s];
    }
    if (tid >= 96) {                           // 160 threads: 2-hop seeds
        const int t = tid - 96;
        const int i = t / 10, s = t - (t / 10) * 10;
        sm_m[i][s] = n2[nfs[i] * 10 + s];
    }
    if (tid < NB) idx[tid][110] = nfs[tid];
    __syncthreads();
    for (int t = tid; t < NB * 100; t += 256) { // 1600 two-hop rows
        const int i = t / 100, rr = t - (t / 100) * 100;
        idx[i][10 + rr] = n1[sm_m[i][rr / 10] * 10 + (rr - (rr / 10) * 10)];
    }
    __syncthreads();

    // ---- phase 2: gather (identical loads/math to round-9), write global F ----
    const int g = tid >> 4;    // node_local 0..15
    const int l = tid & 15;    // dims l*8 .. l*8+7
    const unsigned short* Tl = T + l * 8;

    float aA[8] = {0,0,0,0,0,0,0,0};
    float aB[8] = {0,0,0,0,0,0,0,0};
    uint4 v[10];

    // chunk 0: rows 0..9 -> 1-hop
#pragma unroll
    for (int s = 0; s < 10; ++s) v[s] = *(const uint4*)(Tl + (size_t)idx[g][s] * FEAT);
#pragma unroll
    for (int s = 0; s < 10; ++s) acc8(aA, v[s]);
    // chunks 1..10: rows 10..109 -> 2-hop
#pragma unroll
    for (int c = 1; c <= 10; ++c) {
#pragma unroll
        for (int s = 0; s < 10; ++s)
            v[s] = *(const uint4*)(Tl + (size_t)idx[g][c * 10 + s] * FEAT);
#pragma unroll
        for (int s = 0; s < 10; ++s) acc8(aB, v[s]);
    }
    const uint4 sv = *(const uint4*)(Tl + (size_t)idx[g][110] * FEAT);

    const int n = blk * NB + g;
    *(uint4*)(F2 + (size_t)n * FEAT + l * 8) = sv;
    *(uint4*)(F0 + (size_t)n * FEAT + l * 8) = pack8(aA, 0.1f);
    *(uint4*)(F1 + (size_t)n * FEAT + l * 8) = pack8(aB, 0.01f);
}

// ---------------- Kernel 2: bf16 MFMA GEMM + ReLU (round-8 verbatim) ----------------
// C[x][y] = relu(sum_d X[x][d] * W[y][d]),  X=[24576][128] bf16 (x = j*8192+n),
// W=[1024][128] bf16 (y = c*128+k).  out flat: n*3072 + c*384 + j*128 + k
__global__ void __launch_bounds__(256) proj_mfma(
    const unsigned short* __restrict__ F,
    const unsigned short* __restrict__ Wp,
    float* __restrict__ out)
{
    __shared__ float st[4][16][65];   // wave-private transpose stage

    const int wave = threadIdx.x >> 6;
    const int lane = threadIdx.x & 63;
    const int xBase = blockIdx.x * 256 + wave * 64;
    const int yBase = blockIdx.y * 64;
    const int r = lane & 15;   // A row / B col within 16-tile
    const int q = lane >> 4;   // k-slot (8 contiguous K elems each)

    f32x4 acc[4][4];
#pragma unroll
    for (int mi = 0; mi < 4; ++mi)
#pragma unroll
        for (int nj = 0; nj < 4; ++nj) acc[mi][nj] = (f32x4){0.f, 0.f, 0.f, 0.f};

    const unsigned short* Arow = F  + (size_t)(xBase + r) * FEAT + q * 8;
    const unsigned short* Brow = Wp + (size_t)(yBase + r) * FEAT + q * 8;

#pragma unroll
    for (int k0 = 0; k0 < 4; ++k0) {           // K step = 32
        bf16x8 a[4], b[4];
#pragma unroll
        for (int mi = 0; mi < 4; ++mi)
            a[mi] = *(const bf16x8*)(Arow + (size_t)mi * 16 * FEAT + k0 * 32);
#pragma unroll
        for (int nj = 0; nj < 4; ++nj)
            b[nj] = *(const bf16x8*)(Brow + (size_t)nj * 16 * FEAT + k0 * 32);
#pragma unroll
        for (int mi = 0; mi < 4; ++mi)
#pragma unroll
            for (int nj = 0; nj < 4; ++nj)
                acc[mi][nj] = __builtin_amdgcn_mfma_f32_16x16x32_bf16(
                    a[mi], b[nj], acc[mi][nj], 0, 0, 0);
    }

    // epilogue: per-wave LDS transpose so each lane stores a contiguous float4.
    // C/D layout: col = lane&15 (r), row = q*4 + reg (m89-verified).
    const int c = yBase >> 7;
    const int kBase = (yBase & 127) + r * 4;
#pragma unroll
    for (int mi = 0; mi < 4; ++mi) {
#pragma unroll
        for (int i = 0; i < 4; ++i)
#pragma unroll
            for (int nj = 0; nj < 4; ++nj)
                st[wave][q * 4 + i][nj * 16 + r] = acc[mi][nj][i];
        // wave-private region: no barrier needed, compiler orders via lgkmcnt
#pragma unroll
        for (int rr = 0; rr < 4; ++rr) {
            const int row = rr * 4 + q;
            const f32x4 vv = *(const f32x4*)&st[wave][row][r * 4];
            const int x = xBase + mi * 16 + row;
            const int n = x & 8191;
            const int j = x >> 13;
            f32x4 o;
            o[0] = fmaxf(vv[0], 0.f); o[1] = fmaxf(vv[1], 0.f);
            o[2] = fmaxf(vv[2], 0.f); o[3] = fmaxf(vv[3], 0.f);
            __builtin_nontemporal_store(o,
                (f32x4*)(out + (size_t)n * 3072 + c * 384 + j * 128 + kBase));
        }
    }
}

extern "C" void kernel_launch(void* const* d_in, const int* in_sizes, int n_in,
                              void* d_out, int out_size, void* d_ws, size_t ws_size,
                              hipStream_t stream) {
    const float* features = (const float*)d_in[0];   // [100000,128] f32
    const float* lw       = (const float*)d_in[1];   // [8,128,128]  f32
    const int*   nodes    = (const int*)d_in[2];     // [1024,8]     i32
    const int*   n1       = (const int*)d_in[3];     // [100000,10]  i32
    const int*   n2       = (const int*)d_in[4];     // [100000,10]  i32
    float*       out      = (float*)d_out;           // [1024,8,8,384] f32

    unsigned short* F  = (unsigned short*)d_ws;              // 3*8192*128 bf16 = 6.3 MB
    unsigned short* Wp = F  + (size_t)3 * N_NODES * FEAT;    // 1024*128 bf16 = 256 KB
    unsigned short* T  = Wp + (size_t)1024 * FEAT;           // 100000*128 bf16 = 25.6 MB

    pack_all<<<FEAT_BLOCKS + 128, 256, 0, stream>>>(features, lw, T, Wp);
    gather16<<<NBLK, 256, 0, stream>>>(T, nodes, n1, n2,
                                       F, F + (size_t)N_NODES * FEAT,
                                       F + (size_t)2 * N_NODES * FEAT);
    dim3 grid(24576 / 256, 1024 / 64);   // 96 x 16
    proj_mfma<<<grid, 256, 0, stream>>>(F, Wp, out);
}

// Round 11
// 72.717 us; speedup vs baseline: 1.1443x; 1.1443x over previous
//
#include <hip/hip_runtime.h>

typedef __attribute__((ext_vector_type(8))) short bf16x8;
typedef __attribute__((ext_vector_type(4))) float f32x4;

static constexpr int N_NODES = 8192;   // B*L
static constexpr int FEAT    = 128;
static constexpr int NB      = 16;     // nodes per fused block
static constexpr int NBLK    = N_NODES / NB;   // 512 blocks
static constexpr int XS      = 136;    // LDS X row stride (bf16): 272B, 16B-aligned
static constexpr int FEAT_BLOCKS = 6250;  // 100000*128/8 floats / 256 threads

__device__ __forceinline__ unsigned short f2bf(float f) {
    unsigned u = __builtin_bit_cast(unsigned, f);
    u += 0x7FFFu + ((u >> 16) & 1u);   // round-to-nearest-even
    return (unsigned short)(u >> 16);
}
__device__ __forceinline__ float bf2f(unsigned short h) {
    return __builtin_bit_cast(float, ((unsigned)h) << 16);
}
__device__ __forceinline__ void acc8(float* a, const uint4 v) {
    a[0] += bf2f((unsigned short)(v.x & 0xffffu));
    a[1] += bf2f((unsigned short)(v.x >> 16));
    a[2] += bf2f((unsigned short)(v.y & 0xffffu));
    a[3] += bf2f((unsigned short)(v.y >> 16));
    a[4] += bf2f((unsigned short)(v.z & 0xffffu));
    a[5] += bf2f((unsigned short)(v.z >> 16));
    a[6] += bf2f((unsigned short)(v.w & 0xffffu));
    a[7] += bf2f((unsigned short)(v.w >> 16));
}
__device__ __forceinline__ uint4 pack8(const float* a, float sc) {
    uint4 o;
    o.x = (unsigned)f2bf(a[0] * sc) | ((unsigned)f2bf(a[1] * sc) << 16);
    o.y = (unsigned)f2bf(a[2] * sc) | ((unsigned)f2bf(a[3] * sc) << 16);
    o.z = (unsigned)f2bf(a[4] * sc) | ((unsigned)f2bf(a[5] * sc) << 16);
    o.w = (unsigned)f2bf(a[6] * sc) | ((unsigned)f2bf(a[7] * sc) << 16);
    return o;
}

// ---------------- Kernel 0: pack features + W fp32 -> bf16 ----------------
__global__ void __launch_bounds__(256) pack_all(
    const float* __restrict__ feat, const float* __restrict__ lw,
    unsigned short* __restrict__ T, unsigned short* __restrict__ Wp)
{
    const int b = blockIdx.x;
    if (b < FEAT_BLOCKS) {
        const size_t i = (size_t)b * 256 + threadIdx.x;
        const f32x4* src = (const f32x4*)feat;
        const f32x4 v0 = __builtin_nontemporal_load(src + i * 2);
        const f32x4 v1 = __builtin_nontemporal_load(src + i * 2 + 1);
        ushort4 o0, o1;
        o0.x = f2bf(v0[0]); o0.y = f2bf(v0[1]); o0.z = f2bf(v0[2]); o0.w = f2bf(v0[3]);
        o1.x = f2bf(v1[0]); o1.y = f2bf(v1[1]); o1.z = f2bf(v1[2]); o1.w = f2bf(v1[3]);
        ((ushort4*)T)[i * 2]     = o0;
        ((ushort4*)T)[i * 2 + 1] = o1;
    } else {
        const int i = (b - FEAT_BLOCKS) * 256 + threadIdx.x;
        const float4 v = ((const float4*)lw)[i];
        ushort4 o;
        o.x = f2bf(v.x); o.y = f2bf(v.y); o.z = f2bf(v.z); o.w = f2bf(v.w);
        ((ushort4*)Wp)[i] = o;
    }
}

// ---------------- Fused: gather -> LDS X -> MFMA GEMM + ReLU ----------------
// Phases 1-2 are round-10-verified verbatim (write to LDS X instead of F).
// Phase 3: M=48 x N=1024 x K=128 MFMA with scattered-scalar epilogue
// (round-3-verified store pattern).
__global__ void __launch_bounds__(256) fused_enc(
    const unsigned short* __restrict__ T,
    const int*   __restrict__ nodes,
    const int*   __restrict__ n1,
    const int*   __restrict__ n2,
    const unsigned short* __restrict__ Wp,
    float* __restrict__ out)
{
    __shared__ int nfs[NB];
    __shared__ int sm_m[NB][10];
    __shared__ int idx[NB][112];              // [0..9]=1hop, [10..109]=2hop, [110]=self
    __shared__ unsigned short X[3 * NB][XS];  // 48 x 136 bf16

    const int blk = blockIdx.x;
    const int tid = threadIdx.x;

    // ---- phase 1: indices (round-10-verified) ----
    if (tid < NB) nfs[tid] = nodes[blk * NB + tid];
    __syncthreads();
    if (tid < NB * 10) {                       // 160 threads: 1-hop
        const int i = tid / 10, s = tid - (tid / 10) * 10;
        idx[i][s] = n1[nfs[i] * 10 + s];
    }
    if (tid >= 96) {                           // 160 threads: 2-hop seeds
        const int t = tid - 96;
        const int i = t / 10, s = t - (t / 10) * 10;
        sm_m[i][s] = n2[nfs[i] * 10 + s];
    }
    if (tid < NB) idx[tid][110] = nfs[tid];
    __syncthreads();
    for (int t = tid; t < NB * 100; t += 256) { // 1600 two-hop rows
        const int i = t / 100, rr = t - (t / 100) * 100;
        idx[i][10 + rr] = n1[sm_m[i][rr / 10] * 10 + (rr - (rr / 10) * 10)];
    }
    __syncthreads();

    // ---- phase 2: gather (round-10-verified), write LDS X ----
    {
        const int g = tid >> 4;    // node_local 0..15
        const int l = tid & 15;    // dims l*8 .. l*8+7
        const unsigned short* Tl = T + l * 8;

        float aA[8] = {0,0,0,0,0,0,0,0};
        float aB[8] = {0,0,0,0,0,0,0,0};
        uint4 v[10];

#pragma unroll
        for (int s = 0; s < 10; ++s) v[s] = *(const uint4*)(Tl + (size_t)idx[g][s] * FEAT);
#pragma unroll
        for (int s = 0; s < 10; ++s) acc8(aA, v[s]);
#pragma unroll
        for (int c = 1; c <= 10; ++c) {
#pragma unroll
            for (int s = 0; s < 10; ++s)
                v[s] = *(const uint4*)(Tl + (size_t)idx[g][c * 10 + s] * FEAT);
#pragma unroll
            for (int s = 0; s < 10; ++s) acc8(aB, v[s]);
        }
        const uint4 sv = *(const uint4*)(Tl + (size_t)idx[g][110] * FEAT);
        *(uint4*)&X[g * 3 + 2][l * 8] = sv;
        *(uint4*)&X[g * 3 + 0][l * 8] = pack8(aA, 0.1f);
        *(uint4*)&X[g * 3 + 1][l * 8] = pack8(aB, 0.01f);
    }
    __syncthreads();

    // ---- phase 3: GEMM M=48 x N=1024 x K=128 + ReLU, scattered epilogue ----
    const int wave = tid >> 6;
    const int lane = tid & 63;
    const int r = lane & 15;   // A row / B col within 16-tile
    const int q = lane >> 4;   // k-slot (8 contiguous K elems)

#pragma unroll
    for (int ch = 0; ch < 4; ++ch) {
        const int yBase = wave * 256 + ch * 64;
        f32x4 acc[3][4];
#pragma unroll
        for (int mt = 0; mt < 3; ++mt)
#pragma unroll
            for (int nj = 0; nj < 4; ++nj) acc[mt][nj] = (f32x4){0.f, 0.f, 0.f, 0.f};

#pragma unroll
        for (int k0 = 0; k0 < 4; ++k0) {
            bf16x8 a[3], b[4];
#pragma unroll
            for (int mt = 0; mt < 3; ++mt)
                a[mt] = *(const bf16x8*)&X[mt * 16 + r][k0 * 32 + q * 8];
#pragma unroll
            for (int nj = 0; nj < 4; ++nj)
                b[nj] = *(const bf16x8*)(Wp + (size_t)(yBase + nj * 16 + r) * FEAT
                                            + q * 8 + k0 * 32);
#pragma unroll
            for (int mt = 0; mt < 3; ++mt)
#pragma unroll
                for (int nj = 0; nj < 4; ++nj)
                    acc[mt][nj] = __builtin_amdgcn_mfma_f32_16x16x32_bf16(
                        a[mt], b[nj], acc[mt][nj], 0, 0, 0);
        }

        // round-3-verified scattered epilogue: C/D row = q*4+i, col = r.
#pragma unroll
        for (int mt = 0; mt < 3; ++mt) {
#pragma unroll
            for (int i = 0; i < 4; ++i) {
                const int xl = mt * 16 + q * 4 + i;   // 0..47
                const int nl = xl / 3;
                const int j  = xl - nl * 3;
                float* orow = out + (size_t)(blk * NB + nl) * 3072 + j * 128;
#pragma unroll
                for (int nj = 0; nj < 4; ++nj) {
                    const int y = yBase + nj * 16 + r;
                    const int c = y >> 7;
                    const int k = y & 127;
                    orow[c * 384 + k] = fmaxf(acc[mt][nj][i], 0.f);
                }
            }
        }
    }
}

extern "C" void kernel_launch(void* const* d_in, const int* in_sizes, int n_in,
                              void* d_out, int out_size, void* d_ws, size_t ws_size,
                              hipStream_t stream) {
    const float* features = (const float*)d_in[0];   // [100000,128] f32
    const float* lw       = (const float*)d_in[1];   // [8,128,128]  f32
    const int*   nodes    = (const int*)d_in[2];     // [1024,8]     i32
    const int*   n1       = (const int*)d_in[3];     // [100000,10]  i32
    const int*   n2       = (const int*)d_in[4];     // [100000,10]  i32
    float*       out      = (float*)d_out;           // [1024,8,8,384] f32

    unsigned short* Wp = (unsigned short*)d_ws;              // 1024*128 bf16 = 256 KB
    unsigned short* T  = Wp + (size_t)1024 * FEAT;           // 100000*128 bf16 = 25.6 MB

    pack_all<<<FEAT_BLOCKS + 128, 256, 0, stream>>>(features, lw, T, Wp);
    fused_enc<<<NBLK, 256, 0, stream>>>(T, nodes, n1, n2, Wp, out);
}